// Round 1
// baseline (692.263 us; speedup 1.0000x reference)
//
#include <hip/hip_runtime.h>

#define HDIM 32   // hidden width
#define FDIM 64   // feature width

// Collapse the linear "MLP" (x@W1 + b1)@W2 + b2 into w_eff (64 floats) + b_eff.
// ws layout: [0..63]=w_eff_t, [64..127]=w_eff_c, [128]=b_eff_t, [129]=b_eff_c
__global__ void prep_kernel(const float* __restrict__ Wt1, const float* __restrict__ bt1,
                            const float* __restrict__ Wt2, const float* __restrict__ bt2,
                            const float* __restrict__ Wc1, const float* __restrict__ bc1,
                            const float* __restrict__ Wc2, const float* __restrict__ bc2,
                            float* __restrict__ ws) {
    int tid = threadIdx.x;
    if (tid < 64) {
        const float* W1 = Wt1 + tid * HDIM;
        float s = 0.f;
        #pragma unroll
        for (int h = 0; h < HDIM; ++h) s = fmaf(W1[h], Wt2[h], s);
        ws[tid] = s;
        if (tid == 0) {
            float b = bt2[0];
            #pragma unroll
            for (int h = 0; h < HDIM; ++h) b = fmaf(bt1[h], Wt2[h], b);
            ws[128] = b;
        }
    } else if (tid < 128) {
        int f = tid - 64;
        const float* W1 = Wc1 + f * HDIM;
        float s = 0.f;
        #pragma unroll
        for (int h = 0; h < HDIM; ++h) s = fmaf(W1[h], Wc2[h], s);
        ws[64 + f] = s;
        if (f == 0) {
            float b = bc2[0];
            #pragma unroll
            for (int h = 0; h < HDIM; ++h) b = fmaf(bc1[h], Wc2[h], b);
            ws[129] = b;
        }
    }
}

// Per-row likelihood in closed form.
//   u   = risk + shape*log(t) - shape*log(scale)
//   e   = exp(u)            (so log S = -e)
//   ld  = u - log t + log(shape) - e     (log density)
//   A   = exp(2 e_t) + exp(2 e_c) - 1    (= y1^-2 + y2^-2 - 1)
//   log cur1 = -1.5 log A + 3 e_t  ;  log cur2 = -1.5 log A + 3 e_c
__device__ __forceinline__ float row_logl(float rt, float rc, float tv, float cv,
                                          float shape_t, float kt, float lsh_t,
                                          float shape_c, float kc, float lsh_c) {
    float lt  = __logf(tv);
    float u_t = fmaf(shape_t, lt, rt) - kt;
    float u_c = fmaf(shape_c, lt, rc) - kc;
    float e_t = __expf(u_t);
    float e_c = __expf(u_c);
    float ld_t = u_t - lt + lsh_t - e_t;
    float ld_c = u_c - lt + lsh_c - e_c;
    float A    = __expf(2.f * e_t) + __expf(2.f * e_c) - 1.f;
    float logA = __logf(A);
    return cv * (ld_t + 3.f * e_t) + (1.f - cv) * (ld_c + 3.f * e_c) - 1.5f * logA;
}

// 16 lanes per row, one float4/lane -> each wave load covers 1KB contiguous.
// 2 rows per lane per iteration (ILP). Block = 256 thr = 4 waves = 32 rows/iter.
__launch_bounds__(256, 8)
__global__ void survival_kernel(const float4* __restrict__ x4,
                                const float* __restrict__ t,
                                const float* __restrict__ c,
                                const float* __restrict__ ws,
                                const float* __restrict__ sh_t, const float* __restrict__ sc_t,
                                const float* __restrict__ sh_c, const float* __restrict__ sc_c,
                                float* __restrict__ out, int n) {
    const int tid       = threadIdx.x;
    const int lane      = tid & 63;
    const int sub       = lane & 15;   // float4 column within row
    const int rowInWave = lane >> 4;   // 0..3
    const int waveId    = tid >> 6;    // 0..3

    const float4 wt = ((const float4*)ws)[sub];
    const float4 wc = ((const float4*)ws)[16 + sub];
    const float bt = ws[128];
    const float bc = ws[129];

    const float shape_t = sh_t[0], scale_t = sc_t[0];
    const float shape_c = sh_c[0], scale_c = sc_c[0];
    const float kt    = shape_t * __logf(scale_t);
    const float kc    = shape_c * __logf(scale_c);
    const float lsh_t = __logf(shape_t);
    const float lsh_c = __logf(shape_c);

    float acc = 0.f;

    const int stride = (int)gridDim.x * 32;
    for (int base = (int)blockIdx.x * 32; base < n; base += stride) {
        int r0 = base + waveId * 8 + rowInWave;  // wave covers rows [base+8w, base+8w+8)
        int r1 = r0 + 4;
        float4 xv0 = make_float4(0.f, 0.f, 0.f, 0.f);
        float4 xv1 = xv0;
        if (r0 < n) xv0 = x4[r0 * 16 + sub];
        if (r1 < n) xv1 = x4[r1 * 16 + sub];

        float pt0 = fmaf(xv0.x, wt.x, fmaf(xv0.y, wt.y, fmaf(xv0.z, wt.z, xv0.w * wt.w)));
        float pc0 = fmaf(xv0.x, wc.x, fmaf(xv0.y, wc.y, fmaf(xv0.z, wc.z, xv0.w * wc.w)));
        float pt1 = fmaf(xv1.x, wt.x, fmaf(xv1.y, wt.y, fmaf(xv1.z, wt.z, xv1.w * wt.w)));
        float pc1 = fmaf(xv1.x, wc.x, fmaf(xv1.y, wc.y, fmaf(xv1.z, wc.z, xv1.w * wc.w)));

        #pragma unroll
        for (int m = 8; m >= 1; m >>= 1) {
            pt0 += __shfl_xor(pt0, m);
            pc0 += __shfl_xor(pc0, m);
            pt1 += __shfl_xor(pt1, m);
            pc1 += __shfl_xor(pc1, m);
        }

        if (sub == 0) {
            if (r0 < n)
                acc += row_logl(pt0 + bt, pc0 + bc, t[r0], c[r0],
                                shape_t, kt, lsh_t, shape_c, kc, lsh_c);
            if (r1 < n)
                acc += row_logl(pt1 + bt, pc1 + bc, t[r1], c[r1],
                                shape_t, kt, lsh_t, shape_c, kc, lsh_c);
        }
    }

    // wave reduce
    #pragma unroll
    for (int m = 32; m >= 1; m >>= 1) acc += __shfl_xor(acc, m);

    __shared__ float smem[4];
    if (lane == 0) smem[waveId] = acc;
    __syncthreads();
    if (tid == 0) {
        float s = smem[0] + smem[1] + smem[2] + smem[3];
        atomicAdd(out, s);
    }
}

extern "C" void kernel_launch(void* const* d_in, const int* in_sizes, int n_in,
                              void* d_out, int out_size, void* d_ws, size_t ws_size,
                              hipStream_t stream) {
    const float* x   = (const float*)d_in[0];
    const float* t   = (const float*)d_in[1];
    const float* c   = (const float*)d_in[2];
    const float* Wt1 = (const float*)d_in[3];
    const float* bt1 = (const float*)d_in[4];
    const float* Wt2 = (const float*)d_in[5];
    const float* bt2 = (const float*)d_in[6];
    const float* Wc1 = (const float*)d_in[7];
    const float* bc1 = (const float*)d_in[8];
    const float* Wc2 = (const float*)d_in[9];
    const float* bc2 = (const float*)d_in[10];
    const float* sh_t = (const float*)d_in[11];
    const float* sc_t = (const float*)d_in[12];
    const float* sh_c = (const float*)d_in[13];
    const float* sc_c = (const float*)d_in[14];

    float* out = (float*)d_out;
    float* ws  = (float*)d_ws;
    const int n = in_sizes[1];  // N rows

    hipMemsetAsync(out, 0, sizeof(float), stream);

    prep_kernel<<<1, 128, 0, stream>>>(Wt1, bt1, Wt2, bt2, Wc1, bc1, Wc2, bc2, ws);

    const int grid = 4096;
    survival_kernel<<<grid, 256, 0, stream>>>((const float4*)x, t, c, ws,
                                              sh_t, sc_t, sh_c, sc_c, out, n);
}

// Round 2
// 683.507 us; speedup vs baseline: 1.0128x; 1.0128x over previous
//
#include <hip/hip_runtime.h>

#define HDIM 32   // hidden width
#define FDIM 64   // feature width

// Sum across each quad (4 lanes) using DPP quad_perm — pure VALU, no DS pipe.
// After both steps every lane in the quad holds the quad sum.
__device__ __forceinline__ float quad_sum(float x) {
    int v = __builtin_amdgcn_update_dpp(0, __float_as_int(x), 0xB1, 0xF, 0xF, true); // xor1
    x += __int_as_float(v);
    v = __builtin_amdgcn_update_dpp(0, __float_as_int(x), 0x4E, 0xF, 0xF, true);     // xor2
    x += __int_as_float(v);
    return x;
}

__device__ __forceinline__ float dot4(float4 a, float4 b) {
    return fmaf(a.x, b.x, fmaf(a.y, b.y, fmaf(a.z, b.z, a.w * b.w)));
}

// Per-row likelihood in closed form (theta = 2):
//   u   = risk + shape*log(t) - shape*log(scale)
//   e   = exp(u)            (log S = -e)
//   ld  = u - log t + log(shape) - e
//   A   = exp(2 e_t) + exp(2 e_c) - 1
//   logL = c*(ld_t + 3 e_t) + (1-c)*(ld_c + 3 e_c) - 1.5 log A
__device__ __forceinline__ float row_logl(float rt, float rc, float tv, float cv,
                                          float shape_t, float kt, float lsh_t,
                                          float shape_c, float kc, float lsh_c) {
    float lt  = __logf(tv);
    float u_t = fmaf(shape_t, lt, rt) - kt;
    float u_c = fmaf(shape_c, lt, rc) - kc;
    float e_t = __expf(u_t);
    float e_c = __expf(u_c);
    float ld_t = u_t - lt + lsh_t - e_t;
    float ld_c = u_c - lt + lsh_c - e_c;
    float A    = __expf(2.f * e_t) + __expf(2.f * e_c) - 1.f;
    float logA = __logf(A);
    return cv * (ld_t + 3.f * e_t) + (1.f - cv) * (ld_c + 3.f * e_c) - 1.5f * logA;
}

// 4 lanes per row: lane loads 4 float4 (16 floats) of its row -> 4 loads in
// flight per thread. Quad DPP reduce for the two dots. Wave covers 16 rows,
// block (4 waves) covers 64 rows per iteration.
__launch_bounds__(256)
__global__ void survival_kernel(const float4* __restrict__ x4,
                                const float* __restrict__ t,
                                const float* __restrict__ cv,
                                const float* __restrict__ Wt1, const float* __restrict__ bt1,
                                const float* __restrict__ Wt2, const float* __restrict__ bt2,
                                const float* __restrict__ Wc1, const float* __restrict__ bc1,
                                const float* __restrict__ Wc2, const float* __restrict__ bc2,
                                const float* __restrict__ sh_t, const float* __restrict__ sc_t,
                                const float* __restrict__ sh_c, const float* __restrict__ sc_c,
                                float* __restrict__ out, int n) {
    // ---- cooperative weight collapse: w_eff = W1 @ W2, b_eff = b1 @ W2 + b2 ----
    __shared__ __align__(16) float ws[132];   // [0..63] w_t, [64..127] w_c, [128]=b_t, [129]=b_c
    __shared__ float wsum[4];
    const int tid = threadIdx.x;
    if (tid < 128) {
        const float* W1 = (tid < 64) ? (Wt1 + tid * HDIM) : (Wc1 + (tid - 64) * HDIM);
        const float* W2 = (tid < 64) ? Wt2 : Wc2;
        float s = 0.f;
        #pragma unroll
        for (int h = 0; h < HDIM; ++h) s = fmaf(W1[h], W2[h], s);
        ws[tid] = s;
    } else if (tid < 130) {
        const float* b1 = (tid == 128) ? bt1 : bc1;
        const float* W2 = (tid == 128) ? Wt2 : Wc2;
        float b = (tid == 128) ? bt2[0] : bc2[0];
        #pragma unroll
        for (int h = 0; h < HDIM; ++h) b = fmaf(b1[h], W2[h], b);
        ws[tid] = b;
    }
    __syncthreads();

    const int lane   = tid & 63;
    const int c4     = lane & 3;        // float4-column group within row
    const int g      = lane >> 2;       // row within wave tile (0..15)
    const int waveId = tid >> 6;
    const int rowInBlock = waveId * 16 + g;   // 0..63

    // per-thread weight fragments: columns {c4, c4+4, c4+8, c4+12}
    const float4* wsv = (const float4*)ws;
    const float4 wt0 = wsv[c4],      wt1v = wsv[c4 + 4],
                 wt2v = wsv[c4 + 8], wt3v = wsv[c4 + 12];
    const float4 wc0 = wsv[16 + c4],     wc1v = wsv[16 + c4 + 4],
                 wc2v = wsv[16 + c4 + 8], wc3v = wsv[16 + c4 + 12];
    const float bt = ws[128];
    const float bc = ws[129];

    const float shape_t = sh_t[0], scale_t = sc_t[0];
    const float shape_c = sh_c[0], scale_c = sc_c[0];
    const float kt    = shape_t * __logf(scale_t);
    const float kc    = shape_c * __logf(scale_c);
    const float lsh_t = __logf(shape_t);
    const float lsh_c = __logf(shape_c);

    float acc = 0.f;

    const int stride = (int)gridDim.x * 64;
    for (int base = (int)blockIdx.x * 64; base < n; base += stride) {
        const int R = base + rowInBlock;
        float4 x0 = make_float4(0.f, 0.f, 0.f, 0.f), x1 = x0, x2 = x0, x3 = x0;
        if (R < n) {
            const float4* p = x4 + (size_t)R * 16 + c4;
            x0 = p[0];   // byte offsets 0, 64, 128, 192 — dwordx4 w/ imm offset
            x1 = p[4];
            x2 = p[8];
            x3 = p[12];
        }
        float pt = dot4(x0, wt0) + dot4(x1, wt1v) + dot4(x2, wt2v) + dot4(x3, wt3v);
        float pc = dot4(x0, wc0) + dot4(x1, wc1v) + dot4(x2, wc2v) + dot4(x3, wc3v);
        pt = quad_sum(pt);
        pc = quad_sum(pc);

        if (c4 == 0 && R < n) {
            acc += row_logl(pt + bt, pc + bc, t[R], cv[R],
                            shape_t, kt, lsh_t, shape_c, kc, lsh_c);
        }
    }

    // wave reduce (cold path)
    #pragma unroll
    for (int m = 32; m >= 1; m >>= 1) acc += __shfl_xor(acc, m);
    if (lane == 0) wsum[waveId] = acc;
    __syncthreads();
    if (tid == 0) atomicAdd(out, wsum[0] + wsum[1] + wsum[2] + wsum[3]);
}

extern "C" void kernel_launch(void* const* d_in, const int* in_sizes, int n_in,
                              void* d_out, int out_size, void* d_ws, size_t ws_size,
                              hipStream_t stream) {
    const float* x   = (const float*)d_in[0];
    const float* t   = (const float*)d_in[1];
    const float* c   = (const float*)d_in[2];
    const float* Wt1 = (const float*)d_in[3];
    const float* bt1 = (const float*)d_in[4];
    const float* Wt2 = (const float*)d_in[5];
    const float* bt2 = (const float*)d_in[6];
    const float* Wc1 = (const float*)d_in[7];
    const float* bc1 = (const float*)d_in[8];
    const float* Wc2 = (const float*)d_in[9];
    const float* bc2 = (const float*)d_in[10];
    const float* sh_t = (const float*)d_in[11];
    const float* sc_t = (const float*)d_in[12];
    const float* sh_c = (const float*)d_in[13];
    const float* sc_c = (const float*)d_in[14];

    float* out = (float*)d_out;
    const int n = in_sizes[1];  // N rows

    hipMemsetAsync(out, 0, sizeof(float), stream);

    const int grid = 4096;
    survival_kernel<<<grid, 256, 0, stream>>>((const float4*)x, t, c,
                                              Wt1, bt1, Wt2, bt2,
                                              Wc1, bc1, Wc2, bc2,
                                              sh_t, sc_t, sh_c, sc_c, out, n);
}

// Round 3
// 677.717 us; speedup vs baseline: 1.0215x; 1.0085x over previous
//
#include <hip/hip_runtime.h>

#define HDIM 32   // hidden width
#define FDIM 64   // feature width

// Sum across each quad (4 lanes) using DPP quad_perm — pure VALU, no DS pipe.
// After both steps every lane in the quad holds the quad sum.
__device__ __forceinline__ float quad_sum(float x) {
    int v = __builtin_amdgcn_update_dpp(0, __float_as_int(x), 0xB1, 0xF, 0xF, true); // xor1
    x += __int_as_float(v);
    v = __builtin_amdgcn_update_dpp(0, __float_as_int(x), 0x4E, 0xF, 0xF, true);     // xor2
    x += __int_as_float(v);
    return x;
}

__device__ __forceinline__ float dot4(float4 a, float4 b) {
    return fmaf(a.x, b.x, fmaf(a.y, b.y, fmaf(a.z, b.z, a.w * b.w)));
}

// Per-row likelihood in closed form (theta = 2):
//   u   = risk + shape*log(t) - shape*log(scale)
//   e   = exp(u)            (log S = -e)
//   ld  = u - log t + log(shape) - e
//   A   = exp(2 e_t) + exp(2 e_c) - 1
//   logL = c*(ld_t + 3 e_t) + (1-c)*(ld_c + 3 e_c) - 1.5 log A
__device__ __forceinline__ float row_logl(float rt, float rc, float tv, float cv,
                                          float shape_t, float kt, float lsh_t,
                                          float shape_c, float kc, float lsh_c) {
    float lt  = __logf(tv);
    float u_t = fmaf(shape_t, lt, rt) - kt;
    float u_c = fmaf(shape_c, lt, rc) - kc;
    float e_t = __expf(u_t);
    float e_c = __expf(u_c);
    float ld_t = u_t - lt + lsh_t - e_t;
    float ld_c = u_c - lt + lsh_c - e_c;
    float A    = __expf(2.f * e_t) + __expf(2.f * e_c) - 1.f;
    float logA = __logf(A);
    return cv * (ld_t + 3.f * e_t) + (1.f - cv) * (ld_c + 3.f * e_c) - 1.5f * logA;
}

// 4 lanes per row (quad). Each lane handles TWO rows (R and R+16) per
// iteration -> 8 float4 loads in flight per thread, block tile = 128 rows.
// N % 128 == 0 for this problem, so the main loop is completely branch-free;
// a guarded tail path handles the general case.
__launch_bounds__(256)
__global__ void survival_kernel(const float4* __restrict__ x4,
                                const float* __restrict__ t,
                                const float* __restrict__ cv,
                                const float* __restrict__ Wt1, const float* __restrict__ bt1,
                                const float* __restrict__ Wt2, const float* __restrict__ bt2,
                                const float* __restrict__ Wc1, const float* __restrict__ bc1,
                                const float* __restrict__ Wc2, const float* __restrict__ bc2,
                                const float* __restrict__ sh_t, const float* __restrict__ sc_t,
                                const float* __restrict__ sh_c, const float* __restrict__ sc_c,
                                float* __restrict__ out, int n) {
    // ---- cooperative weight collapse: w_eff = W1 @ W2, b_eff = b1 @ W2 + b2 ----
    __shared__ __align__(16) float ws[132];   // [0..63] w_t, [64..127] w_c, [128]=b_t, [129]=b_c
    __shared__ float wsum[4];
    const int tid = threadIdx.x;
    if (tid < 128) {
        const float* W1 = (tid < 64) ? (Wt1 + tid * HDIM) : (Wc1 + (tid - 64) * HDIM);
        const float* W2 = (tid < 64) ? Wt2 : Wc2;
        float s = 0.f;
        #pragma unroll
        for (int h = 0; h < HDIM; ++h) s = fmaf(W1[h], W2[h], s);
        ws[tid] = s;
    } else if (tid < 130) {
        const float* b1 = (tid == 128) ? bt1 : bc1;
        const float* W2 = (tid == 128) ? Wt2 : Wc2;
        float b = (tid == 128) ? bt2[0] : bc2[0];
        #pragma unroll
        for (int h = 0; h < HDIM; ++h) b = fmaf(b1[h], W2[h], b);
        ws[tid] = b;
    }
    __syncthreads();

    const int lane   = tid & 63;
    const int c4     = lane & 3;        // float4-column group within row
    const int g      = lane >> 2;       // row within wave sub-tile (0..15)
    const int waveId = tid >> 6;

    // per-thread weight fragments: columns {c4, c4+4, c4+8, c4+12}
    const float4* wsv = (const float4*)ws;
    const float4 wtA = wsv[c4],          wtB = wsv[c4 + 4],
                 wtC = wsv[c4 + 8],      wtD = wsv[c4 + 12];
    const float4 wcA = wsv[16 + c4],     wcB = wsv[16 + c4 + 4],
                 wcC = wsv[16 + c4 + 8], wcD = wsv[16 + c4 + 12];
    const float bt = ws[128];
    const float bc = ws[129];

    const float shape_t = sh_t[0], scale_t = sc_t[0];
    const float shape_c = sh_c[0], scale_c = sc_c[0];
    const float kt    = shape_t * __logf(scale_t);
    const float kc    = shape_c * __logf(scale_c);
    const float lsh_t = __logf(shape_t);
    const float lsh_c = __logf(shape_c);

    float acc = 0.f;

    const int nfull   = n & ~127;              // full 128-row tiles
    const int stride  = (int)gridDim.x * 128;
    const int rowOff0 = waveId * 32 + g;       // first row this lane handles
    for (int base = (int)blockIdx.x * 128; base < nfull; base += stride) {
        const int R0 = base + rowOff0;         // wave covers [base+32w, +16)
        const int R1 = R0 + 16;                //         and [base+32w+16, +16)
        const float4* p0 = x4 + (size_t)R0 * 16 + c4;
        const float4* p1 = p0 + 256;           // +16 rows
        float4 a0 = p0[0], a1 = p0[4], a2 = p0[8], a3 = p0[12];
        float4 b0 = p1[0], b1 = p1[4], b2 = p1[8], b3 = p1[12];

        float pt0 = dot4(a0, wtA) + dot4(a1, wtB) + dot4(a2, wtC) + dot4(a3, wtD);
        float pc0 = dot4(a0, wcA) + dot4(a1, wcB) + dot4(a2, wcC) + dot4(a3, wcD);
        float pt1 = dot4(b0, wtA) + dot4(b1, wtB) + dot4(b2, wtC) + dot4(b3, wtD);
        float pc1 = dot4(b0, wcA) + dot4(b1, wcB) + dot4(b2, wcC) + dot4(b3, wcD);

        pt0 = quad_sum(pt0);  pc0 = quad_sum(pc0);
        pt1 = quad_sum(pt1);  pc1 = quad_sum(pc1);

        // split epilogue across two lanes of the quad (32/64 lanes active)
        if (c4 == 0) {
            acc += row_logl(pt0 + bt, pc0 + bc, t[R0], cv[R0],
                            shape_t, kt, lsh_t, shape_c, kc, lsh_c);
        } else if (c4 == 1) {
            acc += row_logl(pt1 + bt, pc1 + bc, t[R1], cv[R1],
                            shape_t, kt, lsh_t, shape_c, kc, lsh_c);
        }
    }

    // guarded tail (dead when n % 128 == 0)
    if (nfull < n && blockIdx.x == 0) {
        for (int base = nfull; base < n; base += 64) {
            const int R = base + waveId * 16 + g;
            float4 a0 = make_float4(0.f, 0.f, 0.f, 0.f), a1 = a0, a2 = a0, a3 = a0;
            if (R < n) {
                const float4* p = x4 + (size_t)R * 16 + c4;
                a0 = p[0]; a1 = p[4]; a2 = p[8]; a3 = p[12];
            }
            float pt = dot4(a0, wtA) + dot4(a1, wtB) + dot4(a2, wtC) + dot4(a3, wtD);
            float pc = dot4(a0, wcA) + dot4(a1, wcB) + dot4(a2, wcC) + dot4(a3, wcD);
            pt = quad_sum(pt);
            pc = quad_sum(pc);
            if (c4 == 0 && R < n) {
                acc += row_logl(pt + bt, pc + bc, t[R], cv[R],
                                shape_t, kt, lsh_t, shape_c, kc, lsh_c);
            }
        }
    }

    // wave reduce (cold path)
    #pragma unroll
    for (int m = 32; m >= 1; m >>= 1) acc += __shfl_xor(acc, m);
    if (lane == 0) wsum[waveId] = acc;
    __syncthreads();
    if (tid == 0) atomicAdd(out, wsum[0] + wsum[1] + wsum[2] + wsum[3]);
}

extern "C" void kernel_launch(void* const* d_in, const int* in_sizes, int n_in,
                              void* d_out, int out_size, void* d_ws, size_t ws_size,
                              hipStream_t stream) {
    const float* x   = (const float*)d_in[0];
    const float* t   = (const float*)d_in[1];
    const float* c   = (const float*)d_in[2];
    const float* Wt1 = (const float*)d_in[3];
    const float* bt1 = (const float*)d_in[4];
    const float* Wt2 = (const float*)d_in[5];
    const float* bt2 = (const float*)d_in[6];
    const float* Wc1 = (const float*)d_in[7];
    const float* bc1 = (const float*)d_in[8];
    const float* Wc2 = (const float*)d_in[9];
    const float* bc2 = (const float*)d_in[10];
    const float* sh_t = (const float*)d_in[11];
    const float* sc_t = (const float*)d_in[12];
    const float* sh_c = (const float*)d_in[13];
    const float* sc_c = (const float*)d_in[14];

    float* out = (float*)d_out;
    const int n = in_sizes[1];  // N rows

    hipMemsetAsync(out, 0, sizeof(float), stream);

    const int grid = 2048;   // 15625 tiles / 2048 ≈ 7.6 iters/block — smooth finish
    survival_kernel<<<grid, 256, 0, stream>>>((const float4*)x, t, c,
                                              Wt1, bt1, Wt2, bt2,
                                              Wc1, bc1, Wc2, bc2,
                                              sh_t, sc_t, sh_c, sc_c, out, n);
}